// Round 6
// baseline (87.584 us; speedup 1.0000x reference)
//
#include <hip/hip_runtime.h>
#include <hip/hip_fp16.h>

typedef unsigned int u32;
typedef _Float16 half2v __attribute__((ext_vector_type(2)));
union H2 { u32 u; half2v v; };

#define MSAMP 1535
#define NS 1024          // samples computed per ray (max chord = 887)
#define RADF 1.3f
#define STEPF ((float)(1.3 * 2.0 / 32.0 / 8.0 / 2.0))

// ---- k_t: transpose atoms fp32 [512 cell][16 a][28 d] -> fp16 [7 s][512 cell][4 j][16 a]
// coalesced reads, scattered 2B writes (write-combine in L2, no stall)
__global__ __launch_bounds__(256) void k_t(const float* __restrict__ atoms,
                                           __half* __restrict__ wst) {
    int o = blockIdx.x * 256 + threadIdx.x;   // 229376 total
    float v = atoms[o];
    int cell = o / 448;            // 448 = 16 atoms * 28 dims
    int r = o - cell * 448;
    int a = r / 28;
    int d = r - a * 28;
    int s = d >> 2, j = d & 3;
    wst[s * 32768 + cell * 64 + j * 16 + a] = __float2half(v);
}

// ---- k_p1: block = (slice s, ray-pair); atoms slice in LDS; 2 rays, 4 samples/thread ----
__global__ __launch_bounds__(512) void k_p1(const float* __restrict__ ro,
                                            const float* __restrict__ rd,
                                            const float* __restrict__ gridf,
                                            const __half* __restrict__ wst,
                                            __half* __restrict__ raw) {
    // 512 cells * 68 halfs (64 data + 4 pad) = 69,632 B; stride 136 B == 34 dw
    // -> 34 mod 32 = 2: cells c and c+16 alias (2-way, free per m136)
    __shared__ __half hl[512 * 68];
    int bx = blockIdx.x;          // 448 = 7 slices * 64 ray-pairs
    int s  = bx >> 6;             // slice 0..6
    int pr = bx & 63;             // ray-pair
    int tid = threadIdx.x;
    int ray = pr * 2 + (tid >> 8);
    int q   = tid & 255;

    {   // stage 64 KB slice: uint4 global reads, 2x uint2 LDS writes (8B aligned)
        const uint4* src = (const uint4*)(wst + s * 32768);
#pragma unroll
        for (int it = 0; it < 8; it++) {
            int idx = it * 512 + tid;          // uint4 index (8 halfs)
            uint4 v = src[idx];
            int cell  = idx >> 3;
            int inner = (idx & 7) << 3;        // half offset within cell
            *(uint2*)&hl[cell * 68 + inner]     = make_uint2(v.x, v.y);
            *(uint2*)&hl[cell * 68 + inner + 4] = make_uint2(v.z, v.w);
        }
    }
    __syncthreads();

    float ox = ro[ray * 3 + 0], oy = ro[ray * 3 + 1], oz = ro[ray * 3 + 2];
    float dx = rd[ray * 3 + 0], dy = rd[ray * 3 + 1], dz = rd[ray * 3 + 2];
    float a0 = ( RADF - ox) / dx, b0 = (-RADF - ox) / dx;
    float a1 = ( RADF - oy) / dy, b1 = (-RADF - oy) / dy;
    float a2 = ( RADF - oz) / dz, b2 = (-RADF - oz) / dz;
    float st = fmaxf(fmaxf(fminf(a0, b0), fminf(a1, b1)), fminf(a2, b2));

#pragma unroll
    for (int k = 0; k < 4; k++) {
        int m = q + k * 256;
        float t = st + (float)m * STEPF;
        float px = ox + t * dx, py = oy + t * dy, pz = oz + t * dz;
        bool inb = (px > -RADF) && (px < RADF) && (py > -RADF) && (py < RADF)
                && (pz > -RADF) && (pz < RADF);
        if (!inb) continue;

        const float inv2R = 1.0f / 2.6f;
        float pnx = fminf(fmaxf((px + RADF) * inv2R, 0.0f), 0.999999f);
        float pny = fminf(fmaxf((py + RADF) * inv2R, 0.0f), 0.999999f);
        float pnz = fminf(fmaxf((pz + RADF) * inv2R, 0.0f), 0.999999f);

        float cpx = pnx * 32.0f, cpy = pny * 32.0f, cpz = pnz * 32.0f;
        float cfx = floorf(cpx), cfy = floorf(cpy), cfz = floorf(cpz);
        int cix = (int)cfx, ciy = (int)cfy, ciz = (int)cfz;

        float fpx = (cpx - cfx) * 8.0f - 0.5f;
        float fpy = (cpy - cfy) * 8.0f - 0.5f;
        float fpz = (cpz - cfz) * 8.0f - 0.5f;
        float ffx = floorf(fpx), ffy = floorf(fpy), ffz = floorf(fpz);
        int f0x = (int)ffx, f0y = (int)ffy, f0z = (int)ffz;
        float wx = fpx - ffx, wy = fpy - ffy, wz = fpz - ffz;

        int ixa[2] = { max(f0x, 0), min(f0x + 1, 7) };
        int iya[2] = { max(f0y, 0), min(f0y + 1, 7) };
        int iza[2] = { max(f0z, 0), min(f0z + 1, 7) };
        float wxa[2] = { 1.0f - wx, wx };
        float wya[2] = { 1.0f - wy, wy };
        float wza[2] = { 1.0f - wz, wz };

        // grid coeffs packed as 8 half2
        half2v ch[8];
        {
            const float4* cp = (const float4*)(gridf + (((cix * 32 + ciy) * 32 + ciz) << 4));
            float4 c0 = cp[0], c1 = cp[1], c2 = cp[2], c3 = cp[3];
            ch[0] = half2v{(_Float16)c0.x, (_Float16)c0.y};
            ch[1] = half2v{(_Float16)c0.z, (_Float16)c0.w};
            ch[2] = half2v{(_Float16)c1.x, (_Float16)c1.y};
            ch[3] = half2v{(_Float16)c1.z, (_Float16)c1.w};
            ch[4] = half2v{(_Float16)c2.x, (_Float16)c2.y};
            ch[5] = half2v{(_Float16)c2.z, (_Float16)c2.w};
            ch[6] = half2v{(_Float16)c3.x, (_Float16)c3.y};
            ch[7] = half2v{(_Float16)c3.z, (_Float16)c3.w};
        }

        float acc[4] = {0.0f, 0.0f, 0.0f, 0.0f};

#pragma unroll
        for (int cx = 0; cx < 2; cx++)
#pragma unroll
        for (int cy = 0; cy < 2; cy++)
#pragma unroll
        for (int cz = 0; cz < 2; cz++) {
            float wt = wxa[cx] * wya[cy] * wza[cz];
            int cb = ((ixa[cx] * 8 + iya[cy]) * 8 + iza[cz]) * 68;
            float dd[4] = {0.0f, 0.0f, 0.0f, 0.0f};
#pragma unroll
            for (int g = 0; g < 4; g++) {
#pragma unroll
                for (int j = 0; j < 4; j++) {
                    uint2 qv = *(const uint2*)&hl[cb + j * 16 + g * 4];
                    H2 a0h, a1h; a0h.u = qv.x; a1h.u = qv.y;
                    dd[j] = __builtin_amdgcn_fdot2(a0h.v, ch[2 * g],     dd[j], false);
                    dd[j] = __builtin_amdgcn_fdot2(a1h.v, ch[2 * g + 1], dd[j], false);
                }
            }
#pragma unroll
            for (int j = 0; j < 4; j++) acc[j] = fmaf(wt, dd[j], acc[j]);
        }

        __half2 p0 = __floats2half2_rn(acc[0], acc[1]);
        __half2 p1 = __floats2half2_rn(acc[2], acc[3]);
        uint2 pv;
        pv.x = *(u32*)&p0;
        pv.y = *(u32*)&p1;
        *(uint2*)&raw[(ray * NS + m) * 28 + s * 4] = pv;
    }
}

// ---- k_p2: per-ray SH-dot + sigmoid + alpha + transmittance scan + reductions ----
__global__ __launch_bounds__(1024) void k_p2(const float* __restrict__ ro,
                                             const float* __restrict__ rd,
                                             const __half* __restrict__ raw,
                                             float* __restrict__ rgb_out,
                                             float* __restrict__ alpha_out,
                                             float* __restrict__ depth_out) {
    int ray = blockIdx.x;
    int t = threadIdx.x;
    int lane = t & 63, wave = t >> 6;   // 16 waves

    int abase = ray * MSAMP;
    if (NS + t < MSAMP) alpha_out[abase + NS + t] = 0.0f;

    float ox = ro[ray * 3 + 0], oy = ro[ray * 3 + 1], oz = ro[ray * 3 + 2];
    float dx = rd[ray * 3 + 0], dy = rd[ray * 3 + 1], dz = rd[ray * 3 + 2];
    float a0 = ( RADF - ox) / dx, b0 = (-RADF - ox) / dx;
    float a1 = ( RADF - oy) / dy, b1 = (-RADF - oy) / dy;
    float a2 = ( RADF - oz) / dz, b2 = (-RADF - oz) / dz;
    float st = fmaxf(fmaxf(fminf(a0, b0), fminf(a1, b1)), fminf(a2, b2));
    float nrm = sqrtf(dx * dx + dy * dy + dz * dz);

    float shm[9];
    shm[0] = 0.28209479177387814f;
    shm[1] = -0.4886025119029199f * dy;
    shm[2] =  0.4886025119029199f * dz;
    shm[3] = -0.4886025119029199f * dx;
    shm[4] =  1.0925484305920792f * dx * dy;
    shm[5] = -1.0925484305920792f * dy * dz;
    shm[6] =  0.31539156525252005f * (2.0f * dz * dz - dx * dx - dy * dy);
    shm[7] = -1.0925484305920792f * dx * dz;
    shm[8] =  0.5462742152960396f * (dx * dx - dy * dy);

    int m = t;
    float tm = st + (float)m * STEPF;
    float px = ox + tm * dx, py = oy + tm * dy, pz = oz + tm * dz;
    bool inb = (px > -RADF) && (px < RADF) && (py > -RADF) && (py < RADF)
            && (pz > -RADF) && (pz < RADF);
    float alpha = 0.0f, r0 = 0.0f, r1 = 0.0f, r2 = 0.0f;
    if (inb) {
        const __half* rp = raw + (ray * NS + m) * 28;
        float v[28];
#pragma unroll
        for (int i = 0; i < 7; i++) {
            uint2 qv = *(const uint2*)(rp + i * 4);
            __half2 h0 = *(__half2*)&qv.x;
            __half2 h1 = *(__half2*)&qv.y;
            float2 f0v = __half22float2(h0);
            float2 f1v = __half22float2(h1);
            v[i*4+0] = f0v.x; v[i*4+1] = f0v.y; v[i*4+2] = f1v.x; v[i*4+3] = f1v.y;
        }
        float sigma = fmaxf(v[27], 0.0f);
        alpha = 1.0f - __expf(-sigma * STEPF * nrm);
        float rr[3];
#pragma unroll
        for (int cch = 0; cch < 3; cch++) {
            float sdot = 0.0f;
#pragma unroll
            for (int j = 0; j < 9; j++) sdot = fmaf(shm[j], v[cch * 9 + j], sdot);
            rr[cch] = 1.0f / (1.0f + __expf(-sdot));
        }
        r0 = rr[0]; r1 = rr[1]; r2 = rr[2];
    }
    alpha_out[abase + m] = alpha;

    float p = 1.0f - alpha + 1e-10f;

    float incl = p;
#pragma unroll
    for (int off = 1; off < 64; off <<= 1) {
        float vv = __shfl_up(incl, off);
        if (lane >= off) incl *= vv;
    }
    __shared__ float wprod[16];
    if (lane == 63) wprod[wave] = incl;
    __syncthreads();
    float excl = __shfl_up(incl, 1);
    if (lane == 0) excl = 1.0f;
    for (int w = 0; w < 16; w++) if (w < wave) excl *= wprod[w];

    float trans = excl;
    float w_ = alpha * trans;
    float ra = w_ * r0, ga = w_ * r1, ba = w_ * r2;
    float da = w_ * tm, wsum = w_;

    float vals[5] = { ra, ga, ba, da, wsum };
    __shared__ float wred[16][5];
#pragma unroll
    for (int i = 0; i < 5; i++) {
        float v = vals[i];
        v += __shfl_xor(v, 1);  v += __shfl_xor(v, 2);  v += __shfl_xor(v, 4);
        v += __shfl_xor(v, 8);  v += __shfl_xor(v, 16); v += __shfl_xor(v, 32);
        if (lane == 0) wred[wave][i] = v;
    }
    __syncthreads();
    if (t == 0) {
        float res[5];
#pragma unroll
        for (int i = 0; i < 5; i++) {
            float r_ = 0.0f;
            for (int w = 0; w < 16; w++) r_ += wred[w][i];
            res[i] = r_;
        }
        float omw = 1.0f - res[4];
        rgb_out[ray * 3 + 0] = res[0] + omw;
        rgb_out[ray * 3 + 1] = res[1] + omw;
        rgb_out[ray * 3 + 2] = res[2] + omw;
        depth_out[ray] = res[3];
    }
}

extern "C" void kernel_launch(void* const* d_in, const int* in_sizes, int n_in,
                              void* d_out, int out_size, void* d_ws, size_t ws_size,
                              hipStream_t stream) {
    const float* ro    = (const float*)d_in[0];
    const float* rd    = (const float*)d_in[1];
    const float* grid  = (const float*)d_in[2];
    const float* atoms = (const float*)d_in[3];
    int B = in_sizes[0] / 3;  // 128

    __half* wst = (__half*)d_ws;                             // 229,376 halfs = 458,752 B
    __half* raw = (__half*)((char*)d_ws + 458752);           // 128*1024*28 halfs = 7,340,032 B

    float* out       = (float*)d_out;
    float* rgb_out   = out;
    float* alpha_out = out + B * 3;
    float* depth_out = out + B * 3 + B * MSAMP;

    hipLaunchKernelGGL(k_t,  dim3(896), dim3(256), 0, stream, atoms, wst);
    hipLaunchKernelGGL(k_p1, dim3(448), dim3(512), 0, stream, ro, rd, grid, wst, raw);
    hipLaunchKernelGGL(k_p2, dim3(B),   dim3(1024), 0, stream, ro, rd, raw,
                       rgb_out, alpha_out, depth_out);
}